// Round 3
// baseline (143.357 us; speedup 1.0000x reference)
//
#include <hip/hip_runtime.h>

typedef __attribute__((ext_vector_type(8))) short s16x8;
typedef __attribute__((ext_vector_type(4))) float f32x4;
typedef __attribute__((ext_vector_type(16))) float f32x16;
typedef __attribute__((ext_vector_type(2))) unsigned u32x2;
typedef __attribute__((ext_vector_type(4))) unsigned u32x4;

#define MFMA32(a, b, c) __builtin_amdgcn_mfma_f32_16x16x32_bf16((a), (b), (c), 0, 0, 0)

// 32x32x16 bf16 MFMA (gfx950). Host pass may lack the builtin declaration;
// stub it there (never executed on host).
#if __has_builtin(__builtin_amdgcn_mfma_f32_32x32x16_bf16)
#define MFMA3216(a, b, c) __builtin_amdgcn_mfma_f32_32x32x16_bf16((a), (b), (c), 0, 0, 0)
#else
#define MFMA3216(a, b, c) (c) /* host-pass parse stub */
#endif

#if __has_builtin(__builtin_amdgcn_exp2f)
#define EXP2F(x) __builtin_amdgcn_exp2f(x)
#else
#define EXP2F(x) __exp2f(x)
#endif

#if __has_builtin(__builtin_amdgcn_rcpf)
#define RCPF(x) __builtin_amdgcn_rcpf(x)
#else
#define RCPF(x) (1.0f / (x))
#endif

#define SL2E 0.25507313f  // (1/sqrt(32)) * log2(e)

// pack two f32 -> bf16 pair (RNE)
__device__ __forceinline__ unsigned pkrne(float a, float b) {
  unsigned ua = __builtin_bit_cast(unsigned, a);
  unsigned ub = __builtin_bit_cast(unsigned, b);
  ua += 0x7FFFu + ((ua >> 16) & 1u);
  ub += 0x7FFFu + ((ub >> 16) & 1u);
  return __builtin_amdgcn_perm(ub, ua, 0x07060302u);
}

// pack two f32 -> bf16 pair by TRUNCATION (1 v_perm); bias cancels in p/l
// because l is accumulated (ones-B MFMA) from the SAME truncated bf16
// values PV consumes.
__device__ __forceinline__ unsigned pktrunc(float a, float b) {
  return __builtin_amdgcn_perm(__builtin_bit_cast(unsigned, b),
                               __builtin_bit_cast(unsigned, a), 0x07060302u);
}

__device__ __forceinline__ unsigned short bfr(float f) {
  unsigned u = __builtin_bit_cast(unsigned, f);
  u += 0x7FFFu + ((u >> 16) & 1u);
  return (unsigned short)(u >> 16);
}

// unpack bf16 pair -> f32
__device__ __forceinline__ float bflo(unsigned u) {
  return __builtin_bit_cast(float, u << 16);
}
__device__ __forceinline__ float bfhi(unsigned u) {
  return __builtin_bit_cast(float, u & 0xFFFF0000u);
}

// v_permlane32_swap_b32: out.x = {a.lo32lanes, b.lo32lanes}, out.y =
// {a.hi32lanes, b.hi32lanes} (exchanges a's upper 32 lanes with b's lower 32).
__device__ __forceinline__ u32x2 plswap(unsigned a, unsigned b) {
#if __has_builtin(__builtin_amdgcn_permlane32_swap)
  return __builtin_amdgcn_permlane32_swap(a, b, false, false);
#else
  unsigned sa = (unsigned)__shfl_xor((int)a, 32, 64);
  unsigned sb = (unsigned)__shfl_xor((int)b, 32, 64);
  bool hi = (threadIdx.x & 63) >= 32;
  u32x2 r;
  r.x = hi ? sb : a;
  r.y = hi ? b : sa;
  return r;
#endif
}

// ---------------------------------------------------------------------------
// Prep: transpose+convert fp32 sources into bf16 k-contiguous layouts.
// ---------------------------------------------------------------------------
__global__ __launch_bounds__(256) void prep_kernel(
    const float* __restrict__ x, const float* __restrict__ wqkv,
    const float* __restrict__ wout, ushort* __restrict__ xbf,
    ushort* __restrict__ wT, ushort* __restrict__ woT) {
  const int t = threadIdx.x;
  const int sub = t & 15, grp = t >> 4;
  const int id = blockIdx.x;
  const float* src;
  ushort* dst;
  int src_ld, k0, n0;
  float sc = 1.f;
  if (id < 512) {
    int mt = id & 63, kt = (id >> 6) & 3, b = id >> 8;
    src = x + (size_t)b * 256 * 4096;
    src_ld = 4096;
    dst = xbf + (size_t)b * 4096 * 256;
    k0 = kt * 64;
    n0 = mt * 64;
  } else if (id < 560) {
    int r = id - 512, nt = r % 12, kt = r / 12;
    src = wqkv;
    src_ld = 768;
    dst = wT;
    k0 = kt * 64;
    n0 = nt * 64;
    if (n0 < 256) sc = SL2E;
  } else {
    int r = id - 560, nt = r & 3, kt = r >> 2;
    src = wout;
    src_ld = 256;
    dst = woT;
    k0 = kt * 64;
    n0 = nt * 64;
  }
  const int k = k0 + grp * 4;
  const int n = n0 + sub * 4;
  unsigned d0[4], d1[4];
#pragma unroll
  for (int i = 0; i < 4; ++i) {
    float4 v = *(const float4*)(src + (size_t)(k + i) * src_ld + n);
    d0[i] = pkrne(v.x * sc, v.y * sc);
    d1[i] = pkrne(v.z * sc, v.w * sc);
  }
  u32x2 r0 = {__builtin_amdgcn_perm(d0[1], d0[0], 0x05040100u),
              __builtin_amdgcn_perm(d0[3], d0[2], 0x05040100u)};
  u32x2 r1 = {__builtin_amdgcn_perm(d0[1], d0[0], 0x07060302u),
              __builtin_amdgcn_perm(d0[3], d0[2], 0x07060302u)};
  u32x2 r2 = {__builtin_amdgcn_perm(d1[1], d1[0], 0x05040100u),
              __builtin_amdgcn_perm(d1[3], d1[2], 0x05040100u)};
  u32x2 r3 = {__builtin_amdgcn_perm(d1[1], d1[0], 0x07060302u),
              __builtin_amdgcn_perm(d1[3], d1[2], 0x07060302u)};
  *(u32x2*)(dst + (size_t)(n + 0) * 256 + k) = r0;
  *(u32x2*)(dst + (size_t)(n + 1) * 256 + k) = r1;
  *(u32x2*)(dst + (size_t)(n + 2) * 256 + k) = r2;
  *(u32x2*)(dst + (size_t)(n + 3) * 256 + k) = r3;
}

// ---------------------------------------------------------------------------
// Fused QKV: D[n][tok] = wT(rows n) x xbf(rows tok).
// Q stored [b,h][tok][dd] (unchanged). K and V stored FRAGMENT-LINEAR per
// 64-token tile so attn can load MFMA fragments as contiguous 1KB
// global_load_dwordx4 direct to registers:
//   K: (b*8+h)*131072 + tl*2048 + s*1024 + hK*512 + hi*256 + l5*8 + e
//      where tok-in-tile = s*32 + l5, dd = hK*16 + hi*8 + e
//   V: (b*8+h)*131072 + tl*2048 + s*1024 + hV*512 + hi*256 + d*8 + e
//      where tok-in-tile = s*32 + hV*16 + hi*8 + e, d = dd
// ---------------------------------------------------------------------------
__global__ __launch_bounds__(256) void qkv_kernel(
    const ushort* __restrict__ xbf, const ushort* __restrict__ wT,
    const float* __restrict__ bq, ushort* __restrict__ QG,
    ushort* __restrict__ KG, ushort* __restrict__ VtG) {
  __shared__ __align__(16) ushort Wl[64][40];
  __shared__ __align__(16) ushort Xl[128][40];
  const int t0 = blockIdx.x * 128;
  const int n0 = blockIdx.y * 64;
  const int t = threadIdx.x;
  const int wid = t >> 6, lane = t & 63;
  const int wy = wid >> 1, wx = wid & 1;
  const int quad = lane >> 4, l16 = lane & 15;
  f32x4 acc[2][4] = {};
  const int wr = t >> 2, wsg = t & 3;
  for (int k0 = 0; k0 < 256; k0 += 32) {
    __syncthreads();
    *(uint4*)&Wl[wr][wsg * 8] =
        *(const uint4*)(wT + (size_t)(n0 + wr) * 256 + k0 + wsg * 8);
#pragma unroll
    for (int i = 0; i < 2; ++i) {
      int fid = t + 256 * i, row = fid >> 2, seg = fid & 3;
      *(uint4*)&Xl[row][seg * 8] =
          *(const uint4*)(xbf + (size_t)(t0 + row) * 256 + k0 + seg * 8);
    }
    __syncthreads();
    s16x8 wf[2], xf[4];
#pragma unroll
    for (int i = 0; i < 2; ++i)
      wf[i] = *(const s16x8*)&Wl[32 * wy + 16 * i + l16][quad * 8];
#pragma unroll
    for (int j = 0; j < 4; ++j)
      xf[j] = *(const s16x8*)&Xl[64 * wx + 16 * j + l16][quad * 8];
#pragma unroll
    for (int i = 0; i < 2; ++i)
#pragma unroll
      for (int j = 0; j < 4; ++j) acc[i][j] = MFMA32(wf[i], xf[j], acc[i][j]);
  }
  if (n0 < 256) {
    // Q: [b,h][tok][dd] (unchanged layout)
#pragma unroll
    for (int i = 0; i < 2; ++i) {
      int nb = n0 + 32 * wy + 16 * i + 4 * quad;
      float4 b4 = *(const float4*)(bq + nb);
      float bx0 = b4.x * SL2E, bx1 = b4.y * SL2E, bx2 = b4.z * SL2E,
            bx3 = b4.w * SL2E;
      int h = ((nb & 255) >> 5);
      int dd0 = nb & 31;
#pragma unroll
      for (int j = 0; j < 4; ++j) {
        int tok = t0 + 64 * wx + 16 * j + l16;
        int b = tok >> 12, tokn = tok & 4095;
        u32x2 pk = {pkrne(acc[i][j][0] + bx0, acc[i][j][1] + bx1),
                    pkrne(acc[i][j][2] + bx2, acc[i][j][3] + bx3)};
        *(u32x2*)(QG + ((size_t)(b * 8 + h) * 4096 + tokn) * 32 + dd0) = pk;
      }
    }
  } else if (n0 < 512) {
    // K: fragment-linear. dd0 = 16*i + 4*quad -> hK=i, hi=quad>>1,
    // e0=4*(quad&1).
#pragma unroll
    for (int i = 0; i < 2; ++i) {
      int nb = n0 + 32 * wy + 16 * i + 4 * quad;
      float4 b4 = *(const float4*)(bq + nb);
      float bx0 = b4.x, bx1 = b4.y, bx2 = b4.z, bx3 = b4.w;
      int h = ((nb & 255) >> 5);
      size_t fo = (size_t)i * 512 + (quad >> 1) * 256 + (quad & 1) * 4;
#pragma unroll
      for (int j = 0; j < 4; ++j) {
        int tok = t0 + 64 * wx + 16 * j + l16;
        int b = tok >> 12, tokn = tok & 4095;
        int tl = tokn >> 6, ss = (tokn >> 5) & 1, l5 = tokn & 31;
        u32x2 pk = {pkrne(acc[i][j][0] + bx0, acc[i][j][1] + bx1),
                    pkrne(acc[i][j][2] + bx2, acc[i][j][3] + bx3)};
        *(u32x2*)(KG + (size_t)(b * 8 + h) * 131072 + (size_t)tl * 2048 +
                  ss * 1024 + l5 * 8 + fo) = pk;
      }
    }
  } else {
    // V: fragment-linear.
#pragma unroll
    for (int i = 0; i < 2; ++i) {
      int nb = n0 + 32 * wy + 16 * i + 4 * quad;
      float4 b4 = *(const float4*)(bq + nb);
      float bb[4] = {b4.x, b4.y, b4.z, b4.w};
#pragma unroll
      for (int r = 0; r < 4; ++r) {
        int nn = nb + r - 512;
        int h = nn >> 5, d = nn & 31;
#pragma unroll
        for (int j = 0; j < 4; ++j) {
          int tok = t0 + 64 * wx + 16 * j + l16;
          int b = tok >> 12, tokn = tok & 4095;
          int tl = tokn >> 6, ss = (tokn >> 5) & 1;
          int hV = (tokn >> 4) & 1, hii = (tokn >> 3) & 1, e = tokn & 7;
          VtG[(size_t)(b * 8 + h) * 131072 + (size_t)tl * 2048 + ss * 1024 +
              hV * 512 + hii * 256 + d * 8 + e] = bfr(acc[i][j][r] + bb[r]);
        }
      }
    }
  }
}

// ---------------------------------------------------------------------------
// Flash attention, SPLIT-K x2, 32x32 MFMA, BARRIER-FREE.
//
// Round-2 diagnosis: per-iter compute (~230 issue-cyc/wave) << load latency;
// the per-iter __syncthreads + hipcc's vmcnt(0)-before-barrier drained the
// prefetch and lockstepped all 4 waves -> SIMDs idle ~75%. Fix: K/V stored
// fragment-linear in global (see qkv_kernel), so each lane's MFMA fragments
// are contiguous 1KB wave-loads DIRECT to registers. No LDS, no barriers;
// waves drift freely and plain 4-wave/SIMD TLP hides the (L1/L2-resident)
// load latency. K/V working set per XCD ~0.5 MB -> L2-hit.
//
// Math identical to round 2 (same MFMA order): QK^T via mfma(K,Q),
// exp2 in-register, pktrunc, permlane32_swap redistribute, PV + ones-B
// l-MFMA.
// ---------------------------------------------------------------------------
__global__ __launch_bounds__(256, 4) void attn_split(
    const ushort* __restrict__ QG, const ushort* __restrict__ KG,
    const ushort* __restrict__ VtG, ushort* __restrict__ OF0,
    ushort* __restrict__ OFb, float* __restrict__ LF) {
  const int id = blockIdx.x;
  const int bh = (id & 7) * 2 + ((id >> 3) & 1);  // XCD-affine heads
  const int q0 = ((id >> 4) & 31) * 128;
  const int sp = id >> 9;   // split index 0..1
  const int kt0 = sp * 32;  // 32 k-tiles (64 tok each) per split
  const int niter = 32;
  const int t = threadIdx.x;
  const int wid = t >> 6, lane = t & 63;
  const int l5 = lane & 31, hi = lane >> 5;
  const ushort* qp = QG + (size_t)bh * 4096 * 32;
  const ushort* kgp = KG + (size_t)bh * 131072 + (size_t)kt0 * 2048;
  const ushort* vgp = VtG + (size_t)bh * 131072 + (size_t)kt0 * 2048;
  const int qw = q0 + 32 * wid;
  // Q fragments (held in regs): B[dk = h*16 + hi*8 + e][q = l5]
  const ushort* qrow = qp + (size_t)(qw + l5) * 32 + hi * 8;
  const s16x8 qf0 = *(const s16x8*)(qrow);
  const s16x8 qf1 = *(const s16x8*)(qrow + 16);
  f32x16 o = {};
  f32x16 o_l = {};
  const s16x8 ones8 = {(short)0x3F80, (short)0x3F80, (short)0x3F80,
                       (short)0x3F80, (short)0x3F80, (short)0x3F80,
                       (short)0x3F80, (short)0x3F80};
  const int lo8 = lane * 8;
  for (int i = 0; i < niter; ++i) {
    const ushort* kt = kgp + (size_t)i * 2048;
    const ushort* vt = vgp + (size_t)i * 2048;
    // Issue all 8 fragment loads up front (contiguous 1KB each); compiler
    // interleaves waits (counted vmcnt) with compute; no barriers anywhere.
    s16x8 k00 = *(const s16x8*)(kt + lo8);
    s16x8 k01 = *(const s16x8*)(kt + 512 + lo8);
    s16x8 v00 = *(const s16x8*)(vt + lo8);
    s16x8 v01 = *(const s16x8*)(vt + 512 + lo8);
    s16x8 k10 = *(const s16x8*)(kt + 1024 + lo8);
    s16x8 k11 = *(const s16x8*)(kt + 1536 + lo8);
    s16x8 v10 = *(const s16x8*)(vt + 1024 + lo8);
    s16x8 v11 = *(const s16x8*)(vt + 1536 + lo8);
#pragma unroll
    for (int s = 0; s < 2; ++s) {
      const s16x8 ka0 = s ? k10 : k00;
      const s16x8 ka1 = s ? k11 : k01;
      const s16x8 va0 = s ? v10 : v00;
      const s16x8 va1 = s ? v11 : v01;
      f32x16 S = {};
      S = MFMA3216(ka0, qf0, S);
      S = MFMA3216(ka1, qf1, S);
      unsigned w8[8];
#pragma unroll
      for (int ii = 0; ii < 8; ++ii)
        w8[ii] = pktrunc(EXP2F(S[2 * ii]), EXP2F(S[2 * ii + 1]));
      // Redistribute to PV A-operand layout: A[q][k = 8*hi + e] per k-half.
      u32x2 sw0 = plswap(w8[0], w8[2]);
      u32x2 sw1 = plswap(w8[1], w8[3]);
      u32x2 sw2 = plswap(w8[4], w8[6]);
      u32x2 sw3 = plswap(w8[5], w8[7]);
      u32x4 pa0 = {sw0.x, sw1.x, sw0.y, sw1.y};  // k 0..15 of subtile
      u32x4 pa1 = {sw2.x, sw3.x, sw2.y, sw3.y};  // k 16..31
      const s16x8 pA0 = __builtin_bit_cast(s16x8, pa0);
      const s16x8 pA1 = __builtin_bit_cast(s16x8, pa1);
      o = MFMA3216(pA0, va0, o);
      o = MFMA3216(pA1, va1, o);
      // l on the MFMA pipe, same truncated P values (bias cancels in O/l).
      o_l = MFMA3216(pA0, ones8, o_l);
      o_l = MFMA3216(pA1, ones8, o_l);
    }
  }
  // Store un-normalized bf16 partial O + f32 partial l.
  ushort* OFs = (sp == 0) ? OF0 : OFb;
  float* LFs = LF + (size_t)sp * 65536;
#pragma unroll
  for (int r = 0; r < 16; ++r) {
    int q = qw + (r & 3) + 8 * (r >> 2) + 4 * hi;
    OFs[((size_t)bh * 4096 + q) * 32 + l5] = bfr(o[r]);
  }
  // o_l: C[row=q][col=d] with l[q] replicated across d. Lane (l5,hi) holds
  // rows crow(r,hi); lanes l5<16 each store row r=l5 of their hi-half.
  float lval = o_l[0];
#pragma unroll
  for (int r = 1; r < 16; ++r) lval = (l5 == r) ? o_l[r] : lval;
  if (l5 < 16)
    LFs[(size_t)bh * 4096 + qw + (l5 & 3) + 8 * (l5 >> 2) + 4 * hi] = lval;
}

// ---------------------------------------------------------------------------
// Out-proj with fused 2-way split-combine + normalization in the staging.
// ---------------------------------------------------------------------------
__global__ __launch_bounds__(256) void proj_split(
    const ushort* __restrict__ OF0, const ushort* __restrict__ OFb,
    const float* __restrict__ LF, const ushort* __restrict__ woT,
    const float* __restrict__ bo, float* __restrict__ out) {
  __shared__ __align__(16) ushort Wl[64][40];
  __shared__ __align__(16) ushort Xl[128][40];
  const int t0 = blockIdx.x * 128;
  const int c0 = blockIdx.y * 64;
  const int t = threadIdx.x;
  const int wid = t >> 6, lane = t & 63;
  const int wy = wid >> 1, wx = wid & 1;
  const int quad = lane >> 4, l16 = lane & 15;
  f32x4 acc[2][4] = {};
  const int wr = t >> 2, wsg = t & 3;
  const int c8 = (t & 7) * 4;  // dd column (4 ushorts)
  for (int k0 = 0; k0 < 256; k0 += 32) {
    __syncthreads();
    *(uint4*)&Wl[wr][wsg * 8] =
        *(const uint4*)(woT + (size_t)(c0 + wr) * 256 + k0 + wsg * 8);
    const int hh = k0 >> 5;
#pragma unroll
    for (int p = 0; p < 4; ++p) {
      int row = 32 * p + (t >> 3);
      int tok = t0 + row, bb = tok >> 12, tokn = tok & 4095;
      size_t ro = (size_t)(bb * 8 + hh) * 4096 + tokn;
      size_t oi = ro * 32 + c8;
      uint2 a0 = *(const uint2*)(OF0 + oi);
      uint2 a1 = *(const uint2*)(OFb + oi);
      float l = LF[ro] + LF[65536 + ro];
      float inv = RCPF(l);
      f32x4 s;
      s[0] = bflo(a0.x) + bflo(a1.x);
      s[1] = bfhi(a0.x) + bfhi(a1.x);
      s[2] = bflo(a0.y) + bflo(a1.y);
      s[3] = bfhi(a0.y) + bfhi(a1.y);
      s *= inv;
      u32x2 pk = {pkrne(s[0], s[1]), pkrne(s[2], s[3])};
      *(u32x2*)&Xl[row][c8] = pk;
    }
    __syncthreads();
    s16x8 wf[2], xf[4];
#pragma unroll
    for (int i = 0; i < 2; ++i)
      wf[i] = *(const s16x8*)&Wl[32 * wy + 16 * i + l16][quad * 8];
#pragma unroll
    for (int j = 0; j < 4; ++j)
      xf[j] = *(const s16x8*)&Xl[64 * wx + 16 * j + l16][quad * 8];
#pragma unroll
    for (int i = 0; i < 2; ++i)
#pragma unroll
      for (int j = 0; j < 4; ++j) acc[i][j] = MFMA32(wf[i], xf[j], acc[i][j]);
  }
#pragma unroll
  for (int i = 0; i < 2; ++i) {
    int cb = c0 + 32 * wy + 16 * i + 4 * quad;
    float4 b4 = *(const float4*)(bo + cb);
    float bb[4] = {b4.x, b4.y, b4.z, b4.w};
#pragma unroll
    for (int j = 0; j < 4; ++j) {
      int tok = t0 + 64 * wx + 16 * j + l16;
      int b = tok >> 12, tokn = tok & 4095;
#pragma unroll
      for (int r = 0; r < 4; ++r)
        out[((size_t)(b * 256 + cb + r)) * 4096 + tokn] = acc[i][j][r] + bb[r];
    }
  }
}

extern "C" void kernel_launch(void* const* d_in, const int* in_sizes, int n_in,
                              void* d_out, int out_size, void* d_ws, size_t ws_size,
                              hipStream_t stream) {
  (void)in_sizes; (void)n_in; (void)out_size; (void)ws_size;
  const float* x = (const float*)d_in[0];
  const float* wq = (const float*)d_in[1];
  const float* bq = (const float*)d_in[2];
  const float* wo = (const float*)d_in[3];
  const float* bo = (const float*)d_in[4];
  float* out = (float*)d_out;
  ushort* ws = (ushort*)d_ws;
  // ws layout:
  ushort* xbf = ws;                    // [8192][256]  (dead after qkv)
  ushort* OF0 = ws;                    // split0 partial O overlays dead xbf
  ushort* QG  = ws + 2097152;          // [2][8][4096][32]
  ushort* KG  = ws + 4194304;          // fragment-linear tiles
  ushort* VtG = ws + 6291456;          // fragment-linear tiles
  ushort* wT  = ws + 8388608;          // [768][256]
  ushort* woT = ws + 8585216;          // [256][256]
  ushort* OFb = ws + 8650752;          // split1 partial O: 2,097,152 ushorts
  float* LF = (float*)(ws + 12845056); // [2][16][4096] f32
  prep_kernel<<<576, 256, 0, stream>>>(x, wq, wo, xbf, wT, woT);
  qkv_kernel<<<dim3(64, 12), 256, 0, stream>>>(xbf, wT, bq, QG, KG, VtG);
  attn_split<<<1024, 256, 0, stream>>>(QG, KG, VtG, OF0, OFb, LF);
  proj_split<<<dim3(64, 4), 256, 0, stream>>>(OF0, OFb, LF, woT, bo, out);
}

// Round 4
// 136.575 us; speedup vs baseline: 1.0497x; 1.0497x over previous
//
#include <hip/hip_runtime.h>

typedef __attribute__((ext_vector_type(8))) short s16x8;
typedef __attribute__((ext_vector_type(4))) float f32x4;
typedef __attribute__((ext_vector_type(16))) float f32x16;
typedef __attribute__((ext_vector_type(2))) unsigned u32x2;
typedef __attribute__((ext_vector_type(4))) unsigned u32x4;

#define MFMA32(a, b, c) __builtin_amdgcn_mfma_f32_16x16x32_bf16((a), (b), (c), 0, 0, 0)

// 32x32x16 bf16 MFMA (gfx950). Host pass may lack the builtin declaration;
// stub it there (never executed on host).
#if __has_builtin(__builtin_amdgcn_mfma_f32_32x32x16_bf16)
#define MFMA3216(a, b, c) __builtin_amdgcn_mfma_f32_32x32x16_bf16((a), (b), (c), 0, 0, 0)
#else
#define MFMA3216(a, b, c) (c) /* host-pass parse stub */
#endif

#if __has_builtin(__builtin_amdgcn_exp2f)
#define EXP2F(x) __builtin_amdgcn_exp2f(x)
#else
#define EXP2F(x) __exp2f(x)
#endif

#if __has_builtin(__builtin_amdgcn_rcpf)
#define RCPF(x) __builtin_amdgcn_rcpf(x)
#else
#define RCPF(x) (1.0f / (x))
#endif

#define SL2E 0.25507313f  // (1/sqrt(32)) * log2(e)

// pack two f32 -> bf16 pair (RNE)
__device__ __forceinline__ unsigned pkrne(float a, float b) {
  unsigned ua = __builtin_bit_cast(unsigned, a);
  unsigned ub = __builtin_bit_cast(unsigned, b);
  ua += 0x7FFFu + ((ua >> 16) & 1u);
  ub += 0x7FFFu + ((ub >> 16) & 1u);
  return __builtin_amdgcn_perm(ub, ua, 0x07060302u);
}

// pack two f32 -> bf16 pair by TRUNCATION (1 v_perm); bias cancels in p/l
// because l is accumulated (ones-B MFMA) from the SAME truncated bf16
// values PV consumes.
__device__ __forceinline__ unsigned pktrunc(float a, float b) {
  return __builtin_amdgcn_perm(__builtin_bit_cast(unsigned, b),
                               __builtin_bit_cast(unsigned, a), 0x07060302u);
}

__device__ __forceinline__ unsigned short bfr(float f) {
  unsigned u = __builtin_bit_cast(unsigned, f);
  u += 0x7FFFu + ((u >> 16) & 1u);
  return (unsigned short)(u >> 16);
}

// unpack bf16 pair -> f32
__device__ __forceinline__ float bflo(unsigned u) {
  return __builtin_bit_cast(float, u << 16);
}
__device__ __forceinline__ float bfhi(unsigned u) {
  return __builtin_bit_cast(float, u & 0xFFFF0000u);
}

// v_permlane32_swap_b32: out.x = {a.lo32lanes, b.lo32lanes}, out.y =
// {a.hi32lanes, b.hi32lanes} (exchanges a's upper 32 lanes with b's lower 32).
__device__ __forceinline__ u32x2 plswap(unsigned a, unsigned b) {
#if __has_builtin(__builtin_amdgcn_permlane32_swap)
  return __builtin_amdgcn_permlane32_swap(a, b, false, false);
#else
  unsigned sa = (unsigned)__shfl_xor((int)a, 32, 64);
  unsigned sb = (unsigned)__shfl_xor((int)b, 32, 64);
  bool hi = (threadIdx.x & 63) >= 32;
  u32x2 r;
  r.x = hi ? sb : a;
  r.y = hi ? b : sa;
  return r;
#endif
}

// Async global->LDS: per-lane 16B from g (per-lane addr) lands at
// lds_base + lane*16 (wave-uniform base, lane-linear order).
__device__ __forceinline__ void stage16(const ushort* g, ushort* l, int lane) {
#if __has_builtin(__builtin_amdgcn_global_load_lds)
  __builtin_amdgcn_global_load_lds(
      (__attribute__((address_space(1))) unsigned int*)(unsigned long long)(
          const void*)g,
      (__attribute__((address_space(3))) unsigned int*)(unsigned)(
          unsigned long long)(const void*)l,
      16, 0, 0);
#else
  *(uint4*)(l + lane * 8) = *(const uint4*)g;
#endif
}

// ---------------------------------------------------------------------------
// Prep: transpose+convert fp32 sources into bf16 k-contiguous layouts.
// ---------------------------------------------------------------------------
__global__ __launch_bounds__(256) void prep_kernel(
    const float* __restrict__ x, const float* __restrict__ wqkv,
    const float* __restrict__ wout, ushort* __restrict__ xbf,
    ushort* __restrict__ wT, ushort* __restrict__ woT) {
  const int t = threadIdx.x;
  const int sub = t & 15, grp = t >> 4;
  const int id = blockIdx.x;
  const float* src;
  ushort* dst;
  int src_ld, k0, n0;
  float sc = 1.f;
  if (id < 512) {
    int mt = id & 63, kt = (id >> 6) & 3, b = id >> 8;
    src = x + (size_t)b * 256 * 4096;
    src_ld = 4096;
    dst = xbf + (size_t)b * 4096 * 256;
    k0 = kt * 64;
    n0 = mt * 64;
  } else if (id < 560) {
    int r = id - 512, nt = r % 12, kt = r / 12;
    src = wqkv;
    src_ld = 768;
    dst = wT;
    k0 = kt * 64;
    n0 = nt * 64;
    if (n0 < 256) sc = SL2E;
  } else {
    int r = id - 560, nt = r & 3, kt = r >> 2;
    src = wout;
    src_ld = 256;
    dst = woT;
    k0 = kt * 64;
    n0 = nt * 64;
  }
  const int k = k0 + grp * 4;
  const int n = n0 + sub * 4;
  unsigned d0[4], d1[4];
#pragma unroll
  for (int i = 0; i < 4; ++i) {
    float4 v = *(const float4*)(src + (size_t)(k + i) * src_ld + n);
    d0[i] = pkrne(v.x * sc, v.y * sc);
    d1[i] = pkrne(v.z * sc, v.w * sc);
  }
  u32x2 r0 = {__builtin_amdgcn_perm(d0[1], d0[0], 0x05040100u),
              __builtin_amdgcn_perm(d0[3], d0[2], 0x05040100u)};
  u32x2 r1 = {__builtin_amdgcn_perm(d0[1], d0[0], 0x07060302u),
              __builtin_amdgcn_perm(d0[3], d0[2], 0x07060302u)};
  u32x2 r2 = {__builtin_amdgcn_perm(d1[1], d1[0], 0x05040100u),
              __builtin_amdgcn_perm(d1[3], d1[2], 0x05040100u)};
  u32x2 r3 = {__builtin_amdgcn_perm(d1[1], d1[0], 0x07060302u),
              __builtin_amdgcn_perm(d1[3], d1[2], 0x07060302u)};
  *(u32x2*)(dst + (size_t)(n + 0) * 256 + k) = r0;
  *(u32x2*)(dst + (size_t)(n + 1) * 256 + k) = r1;
  *(u32x2*)(dst + (size_t)(n + 2) * 256 + k) = r2;
  *(u32x2*)(dst + (size_t)(n + 3) * 256 + k) = r3;
}

// ---------------------------------------------------------------------------
// Fused QKV: D[n][tok] = wT(rows n) x xbf(rows tok).
// Q stored [b,h][tok][dd]. K and V stored FRAGMENT-LINEAR per 64-token tile
// (1KB chunks in the exact order attn's lanes consume them):
//   K: (b*8+h)*131072 + tl*2048 + s*1024 + hK*512 + hi*256 + l5*8 + e
//   V: (b*8+h)*131072 + tl*2048 + s*1024 + hV*512 + hi*256 + d*8 + e
// ---------------------------------------------------------------------------
__global__ __launch_bounds__(256) void qkv_kernel(
    const ushort* __restrict__ xbf, const ushort* __restrict__ wT,
    const float* __restrict__ bq, ushort* __restrict__ QG,
    ushort* __restrict__ KG, ushort* __restrict__ VtG) {
  __shared__ __align__(16) ushort Wl[64][40];
  __shared__ __align__(16) ushort Xl[128][40];
  const int t0 = blockIdx.x * 128;
  const int n0 = blockIdx.y * 64;
  const int t = threadIdx.x;
  const int wid = t >> 6, lane = t & 63;
  const int wy = wid >> 1, wx = wid & 1;
  const int quad = lane >> 4, l16 = lane & 15;
  f32x4 acc[2][4] = {};
  const int wr = t >> 2, wsg = t & 3;
  for (int k0 = 0; k0 < 256; k0 += 32) {
    __syncthreads();
    *(uint4*)&Wl[wr][wsg * 8] =
        *(const uint4*)(wT + (size_t)(n0 + wr) * 256 + k0 + wsg * 8);
#pragma unroll
    for (int i = 0; i < 2; ++i) {
      int fid = t + 256 * i, row = fid >> 2, seg = fid & 3;
      *(uint4*)&Xl[row][seg * 8] =
          *(const uint4*)(xbf + (size_t)(t0 + row) * 256 + k0 + seg * 8);
    }
    __syncthreads();
    s16x8 wf[2], xf[4];
#pragma unroll
    for (int i = 0; i < 2; ++i)
      wf[i] = *(const s16x8*)&Wl[32 * wy + 16 * i + l16][quad * 8];
#pragma unroll
    for (int j = 0; j < 4; ++j)
      xf[j] = *(const s16x8*)&Xl[64 * wx + 16 * j + l16][quad * 8];
#pragma unroll
    for (int i = 0; i < 2; ++i)
#pragma unroll
      for (int j = 0; j < 4; ++j) acc[i][j] = MFMA32(wf[i], xf[j], acc[i][j]);
  }
  if (n0 < 256) {
    // Q: [b,h][tok][dd]
#pragma unroll
    for (int i = 0; i < 2; ++i) {
      int nb = n0 + 32 * wy + 16 * i + 4 * quad;
      float4 b4 = *(const float4*)(bq + nb);
      float bx0 = b4.x * SL2E, bx1 = b4.y * SL2E, bx2 = b4.z * SL2E,
            bx3 = b4.w * SL2E;
      int h = ((nb & 255) >> 5);
      int dd0 = nb & 31;
#pragma unroll
      for (int j = 0; j < 4; ++j) {
        int tok = t0 + 64 * wx + 16 * j + l16;
        int b = tok >> 12, tokn = tok & 4095;
        u32x2 pk = {pkrne(acc[i][j][0] + bx0, acc[i][j][1] + bx1),
                    pkrne(acc[i][j][2] + bx2, acc[i][j][3] + bx3)};
        *(u32x2*)(QG + ((size_t)(b * 8 + h) * 4096 + tokn) * 32 + dd0) = pk;
      }
    }
  } else if (n0 < 512) {
    // K: fragment-linear. dd0 = 16*i + 4*quad -> hK=i, hi=quad>>1,
    // e0=4*(quad&1).
#pragma unroll
    for (int i = 0; i < 2; ++i) {
      int nb = n0 + 32 * wy + 16 * i + 4 * quad;
      float4 b4 = *(const float4*)(bq + nb);
      float bx0 = b4.x, bx1 = b4.y, bx2 = b4.z, bx3 = b4.w;
      int h = ((nb & 255) >> 5);
      size_t fo = (size_t)i * 512 + (quad >> 1) * 256 + (quad & 1) * 4;
#pragma unroll
      for (int j = 0; j < 4; ++j) {
        int tok = t0 + 64 * wx + 16 * j + l16;
        int b = tok >> 12, tokn = tok & 4095;
        int tl = tokn >> 6, ss = (tokn >> 5) & 1, l5 = tokn & 31;
        u32x2 pk = {pkrne(acc[i][j][0] + bx0, acc[i][j][1] + bx1),
                    pkrne(acc[i][j][2] + bx2, acc[i][j][3] + bx3)};
        *(u32x2*)(KG + (size_t)(b * 8 + h) * 131072 + (size_t)tl * 2048 +
                  ss * 1024 + l5 * 8 + fo) = pk;
      }
    }
  } else {
    // V: fragment-linear.
#pragma unroll
    for (int i = 0; i < 2; ++i) {
      int nb = n0 + 32 * wy + 16 * i + 4 * quad;
      float4 b4 = *(const float4*)(bq + nb);
      float bb[4] = {b4.x, b4.y, b4.z, b4.w};
#pragma unroll
      for (int r = 0; r < 4; ++r) {
        int nn = nb + r - 512;
        int h = nn >> 5, d = nn & 31;
#pragma unroll
        for (int j = 0; j < 4; ++j) {
          int tok = t0 + 64 * wx + 16 * j + l16;
          int b = tok >> 12, tokn = tok & 4095;
          int tl = tokn >> 6, ss = (tokn >> 5) & 1;
          int hV = (tokn >> 4) & 1, hii = (tokn >> 3) & 1, e = tokn & 7;
          VtG[(size_t)(b * 8 + h) * 131072 + (size_t)tl * 2048 + ss * 1024 +
              hV * 512 + hii * 256 + d * 8 + e] = bfr(acc[i][j][r] + bb[r]);
        }
      }
    }
  }
}

// ---------------------------------------------------------------------------
// Flash attention, SPLIT-K x2, 32x32 MFMA, SKEWED SOFTWARE PIPELINE.
//
// Round-2/3 diagnosis: MFMA-busy ~21us and VALU-busy ~26us NEVER overlap
// (sum == wall). Fix: one-subtile skew WITHIN each wave -- issue QK^T MFMAs
// for subtile u, and while they execute run softmax VALU + PV MFMAs of
// subtile u-1 (data-independent). s1's PV crosses the iter barrier, so LDS
// is triple-buffered (24 KiB): buf (i-1)%3 is only overwritten by the stage
// issued at iter i+2, separated by the iter-i+1 barrier.
//
// Staging: global_load_lds width-16 from the fragment-linear K/V layout
// (contiguous 1KB per wave-chunk); one __syncthreads per iter (its vmcnt(0)
// is exactly the prefetch-complete wait, issued a full iter body earlier).
// ---------------------------------------------------------------------------
struct AttnAcc {
  f32x16 o;
  f32x16 o_l;
};

__device__ __forceinline__ void softpv(const f32x16& S, const ushort* vhalf,
                                       int lane, f32x16& o, f32x16& o_l) {
  const s16x8 ones8 = {(short)0x3F80, (short)0x3F80, (short)0x3F80,
                       (short)0x3F80, (short)0x3F80, (short)0x3F80,
                       (short)0x3F80, (short)0x3F80};
  unsigned w8[8];
#pragma unroll
  for (int ii = 0; ii < 8; ++ii)
    w8[ii] = pktrunc(EXP2F(S[2 * ii]), EXP2F(S[2 * ii + 1]));
  u32x2 sw0 = plswap(w8[0], w8[2]);
  u32x2 sw1 = plswap(w8[1], w8[3]);
  u32x2 sw2 = plswap(w8[4], w8[6]);
  u32x2 sw3 = plswap(w8[5], w8[7]);
  u32x4 pa0 = {sw0.x, sw1.x, sw0.y, sw1.y};  // k 0..15 of subtile
  u32x4 pa1 = {sw2.x, sw3.x, sw2.y, sw3.y};  // k 16..31
  const s16x8 pA0 = __builtin_bit_cast(s16x8, pa0);
  const s16x8 pA1 = __builtin_bit_cast(s16x8, pa1);
  const s16x8 va0 = *(const s16x8*)(vhalf + lane * 8);
  const s16x8 va1 = *(const s16x8*)(vhalf + 512 + lane * 8);
  o = MFMA3216(pA0, va0, o);
  o = MFMA3216(pA1, va1, o);
  o_l = MFMA3216(pA0, ones8, o_l);
  o_l = MFMA3216(pA1, ones8, o_l);
}

__global__ __launch_bounds__(256, 4) void attn_split(
    const ushort* __restrict__ QG, const ushort* __restrict__ KG,
    const ushort* __restrict__ VtG, ushort* __restrict__ OF0,
    ushort* __restrict__ OFb, float* __restrict__ LF) {
  __shared__ __align__(64) ushort KVs[3][4096];  // per buf: K 2048, V 2048
  const int id = blockIdx.x;
  const int bh = (id & 7) * 2 + ((id >> 3) & 1);  // XCD-affine heads
  const int q0 = ((id >> 4) & 31) * 128;
  const int sp = id >> 9;   // split index 0..1
  const int kt0 = sp * 32;  // 32 k-tiles (64 tok each) per split
  const int niter = 32;
  const int t = threadIdx.x;
  const int wid = t >> 6, lane = t & 63;
  const int l5 = lane & 31, hi = lane >> 5;
  const ushort* qp = QG + (size_t)bh * 4096 * 32;
  const ushort* kgp = KG + (size_t)bh * 131072 + (size_t)kt0 * 2048;
  const ushort* vgp = VtG + (size_t)bh * 131072 + (size_t)kt0 * 2048;
  const int qw = q0 + 32 * wid;
  // Q fragments (held in regs): B[dk = h*16 + hi*8 + e][q = l5]
  const ushort* qrow = qp + (size_t)(qw + l5) * 32 + hi * 8;
  const s16x8 qf0 = *(const s16x8*)(qrow);
  const s16x8 qf1 = *(const s16x8*)(qrow + 16);
  // Staging assignment: wave wid stages 1KB chunk kdst of K and of V.
  const int kdst = wid * 512;  // ushort offset of this wave's 1KB chunk
  const ushort* kpre = kgp + kdst + lane * 8;
  const ushort* vpre = vgp + kdst + lane * 8;
  stage16(kpre, &KVs[0][kdst], lane);
  stage16(vpre, &KVs[0][2048 + kdst], lane);
  kpre += 2048;
  vpre += 2048;
  __syncthreads();
  f32x16 o = {};
  f32x16 o_l = {};
  f32x16 S1p = {};  // subtile-1 scores of previous tile (live across barrier)
  int b = 0, bm1 = 2, bp1 = 1;
  const int lo8 = lane * 8;
  for (int i = 0; i < niter; ++i) {
    // Prefetch next tile early (latency covered by this whole iter body).
    if (i + 1 < niter) {
      stage16(kpre, &KVs[bp1][kdst], lane);
      stage16(vpre, &KVs[bp1][2048 + kdst], lane);
      kpre += 2048;
      vpre += 2048;
    }
    const ushort* kb = &KVs[b][0];
    // QK^T subtile 0 (issue; executes while prev-softpv runs on VALU)
    const s16x8 ka00 = *(const s16x8*)(kb + lo8);
    const s16x8 ka01 = *(const s16x8*)(kb + 512 + lo8);
    f32x16 S0 = {};
    S0 = MFMA3216(ka00, qf0, S0);
    S0 = MFMA3216(ka01, qf1, S0);
    // Process subtile 1 of PREVIOUS tile (V half s=1 of buf bm1).
    if (i > 0) softpv(S1p, &KVs[bm1][2048 + 1024], lane, o, o_l);
    // QK^T subtile 1 (issue; executes while s0-softpv runs)
    const s16x8 ka10 = *(const s16x8*)(kb + 1024 + lo8);
    const s16x8 ka11 = *(const s16x8*)(kb + 1536 + lo8);
    f32x16 S1 = {};
    S1 = MFMA3216(ka10, qf0, S1);
    S1 = MFMA3216(ka11, qf1, S1);
    // Process subtile 0 of THIS tile (V half s=0 of buf b).
    softpv(S0, &KVs[b][2048], lane, o, o_l);
    S1p = S1;
    __syncthreads();
    bm1 = b;
    b = bp1;
    bp1 = (bp1 + 1 == 3) ? 0 : bp1 + 1;
  }
  // Epilogue: subtile 1 of the last tile.
  softpv(S1p, &KVs[bm1][2048 + 1024], lane, o, o_l);
  // Store un-normalized bf16 partial O + f32 partial l.
  ushort* OFs = (sp == 0) ? OF0 : OFb;
  float* LFs = LF + (size_t)sp * 65536;
#pragma unroll
  for (int r = 0; r < 16; ++r) {
    int q = qw + (r & 3) + 8 * (r >> 2) + 4 * hi;
    OFs[((size_t)bh * 4096 + q) * 32 + l5] = bfr(o[r]);
  }
  // o_l: C[row=q][col=d] with l[q] replicated across d. Lane (l5,hi) holds
  // rows crow(r,hi); lanes l5<16 each store row r=l5 of their hi-half.
  float lval = o_l[0];
#pragma unroll
  for (int r = 1; r < 16; ++r) lval = (l5 == r) ? o_l[r] : lval;
  if (l5 < 16)
    LFs[(size_t)bh * 4096 + qw + (l5 & 3) + 8 * (l5 >> 2) + 4 * hi] = lval;
}

// ---------------------------------------------------------------------------
// Out-proj with fused 2-way split-combine + normalization in the staging.
// 64-token tiles -> grid (128,4) = 512 blocks = 2 blocks/CU (was 1/CU:
// a barriered staging kernel at 12.5% occupancy was latency-exposed).
// ---------------------------------------------------------------------------
__global__ __launch_bounds__(256) void proj_split(
    const ushort* __restrict__ OF0, const ushort* __restrict__ OFb,
    const float* __restrict__ LF, const ushort* __restrict__ woT,
    const float* __restrict__ bo, float* __restrict__ out) {
  __shared__ __align__(16) ushort Wl[64][40];
  __shared__ __align__(16) ushort Xl[64][40];
  const int t0 = blockIdx.x * 64;
  const int c0 = blockIdx.y * 64;
  const int t = threadIdx.x;
  const int wid = t >> 6, lane = t & 63;
  const int wy = wid >> 1, wx = wid & 1;
  const int quad = lane >> 4, l16 = lane & 15;
  f32x4 acc[2][2] = {};
  const int wr = t >> 2, wsg = t & 3;
  const int c8 = (t & 7) * 4;  // dd column (4 ushorts)
  for (int k0 = 0; k0 < 256; k0 += 32) {
    __syncthreads();
    *(uint4*)&Wl[wr][wsg * 8] =
        *(const uint4*)(woT + (size_t)(c0 + wr) * 256 + k0 + wsg * 8);
    const int hh = k0 >> 5;
#pragma unroll
    for (int p = 0; p < 2; ++p) {
      int row = 32 * p + (t >> 3);
      int tok = t0 + row, bb = tok >> 12, tokn = tok & 4095;
      size_t ro = (size_t)(bb * 8 + hh) * 4096 + tokn;
      size_t oi = ro * 32 + c8;
      uint2 a0 = *(const uint2*)(OF0 + oi);
      uint2 a1 = *(const uint2*)(OFb + oi);
      float l = LF[ro] + LF[65536 + ro];
      float inv = RCPF(l);
      f32x4 s;
      s[0] = bflo(a0.x) + bflo(a1.x);
      s[1] = bfhi(a0.x) + bfhi(a1.x);
      s[2] = bflo(a0.y) + bflo(a1.y);
      s[3] = bfhi(a0.y) + bfhi(a1.y);
      s *= inv;
      u32x2 pk = {pkrne(s[0], s[1]), pkrne(s[2], s[3])};
      *(u32x2*)&Xl[row][c8] = pk;
    }
    __syncthreads();
    s16x8 wf[2], xf[2];
#pragma unroll
    for (int i = 0; i < 2; ++i)
      wf[i] = *(const s16x8*)&Wl[32 * wy + 16 * i + l16][quad * 8];
#pragma unroll
    for (int j = 0; j < 2; ++j)
      xf[j] = *(const s16x8*)&Xl[32 * wx + 16 * j + l16][quad * 8];
#pragma unroll
    for (int i = 0; i < 2; ++i)
#pragma unroll
      for (int j = 0; j < 2; ++j) acc[i][j] = MFMA32(wf[i], xf[j], acc[i][j]);
  }
#pragma unroll
  for (int i = 0; i < 2; ++i) {
    int cb = c0 + 32 * wy + 16 * i + 4 * quad;
    float4 b4 = *(const float4*)(bo + cb);
    float bb[4] = {b4.x, b4.y, b4.z, b4.w};
#pragma unroll
    for (int j = 0; j < 2; ++j) {
      int tok = t0 + 32 * wx + 16 * j + l16;
      int b = tok >> 12, tokn = tok & 4095;
#pragma unroll
      for (int r = 0; r < 4; ++r)
        out[((size_t)(b * 256 + cb + r)) * 4096 + tokn] = acc[i][j][r] + bb[r];
    }
  }
}

extern "C" void kernel_launch(void* const* d_in, const int* in_sizes, int n_in,
                              void* d_out, int out_size, void* d_ws, size_t ws_size,
                              hipStream_t stream) {
  (void)in_sizes; (void)n_in; (void)out_size; (void)ws_size;
  const float* x = (const float*)d_in[0];
  const float* wq = (const float*)d_in[1];
  const float* bq = (const float*)d_in[2];
  const float* wo = (const float*)d_in[3];
  const float* bo = (const float*)d_in[4];
  float* out = (float*)d_out;
  ushort* ws = (ushort*)d_ws;
  // ws layout:
  ushort* xbf = ws;                    // [8192][256]  (dead after qkv)
  ushort* OF0 = ws;                    // split0 partial O overlays dead xbf
  ushort* QG  = ws + 2097152;          // [2][8][4096][32]
  ushort* KG  = ws + 4194304;          // fragment-linear tiles
  ushort* VtG = ws + 6291456;          // fragment-linear tiles
  ushort* wT  = ws + 8388608;          // [768][256]
  ushort* woT = ws + 8585216;          // [256][256]
  ushort* OFb = ws + 8650752;          // split1 partial O: 2,097,152 ushorts
  float* LF = (float*)(ws + 12845056); // [2][16][4096] f32
  prep_kernel<<<576, 256, 0, stream>>>(x, wq, wo, xbf, wT, woT);
  qkv_kernel<<<dim3(64, 12), 256, 0, stream>>>(xbf, wT, bq, QG, KG, VtG);
  attn_split<<<1024, 256, 0, stream>>>(QG, KG, VtG, OF0, OFb, LF);
  proj_split<<<dim3(128, 4), 256, 0, stream>>>(OF0, OFb, LF, woT, bo, out);
}

// Round 5
// 134.882 us; speedup vs baseline: 1.0628x; 1.0126x over previous
//
#include <hip/hip_runtime.h>

typedef __attribute__((ext_vector_type(8))) short s16x8;
typedef __attribute__((ext_vector_type(4))) float f32x4;
typedef __attribute__((ext_vector_type(16))) float f32x16;
typedef __attribute__((ext_vector_type(2))) unsigned u32x2;
typedef __attribute__((ext_vector_type(4))) unsigned u32x4;

#define MFMA32(a, b, c) __builtin_amdgcn_mfma_f32_16x16x32_bf16((a), (b), (c), 0, 0, 0)

#if __has_builtin(__builtin_amdgcn_mfma_f32_32x32x16_bf16)
#define MFMA3216(a, b, c) __builtin_amdgcn_mfma_f32_32x32x16_bf16((a), (b), (c), 0, 0, 0)
#else
#define MFMA3216(a, b, c) (c) /* host-pass parse stub */
#endif

#if __has_builtin(__builtin_amdgcn_exp2f)
#define EXP2F(x) __builtin_amdgcn_exp2f(x)
#else
#define EXP2F(x) __exp2f(x)
#endif

#if __has_builtin(__builtin_amdgcn_rcpf)
#define RCPF(x) __builtin_amdgcn_rcpf(x)
#else
#define RCPF(x) (1.0f / (x))
#endif

#define SL2E 0.25507313f  // (1/sqrt(32)) * log2(e)

__device__ __forceinline__ unsigned pkrne(float a, float b) {
  unsigned ua = __builtin_bit_cast(unsigned, a);
  unsigned ub = __builtin_bit_cast(unsigned, b);
  ua += 0x7FFFu + ((ua >> 16) & 1u);
  ub += 0x7FFFu + ((ub >> 16) & 1u);
  return __builtin_amdgcn_perm(ub, ua, 0x07060302u);
}

// pack two f32 -> bf16 pair by TRUNCATION (1 v_perm); bias cancels in O/l
// because l is accumulated (ones-B MFMA) from the SAME truncated bf16 values.
__device__ __forceinline__ unsigned pktrunc(float a, float b) {
  return __builtin_amdgcn_perm(__builtin_bit_cast(unsigned, b),
                               __builtin_bit_cast(unsigned, a), 0x07060302u);
}

__device__ __forceinline__ unsigned short bfr(float f) {
  unsigned u = __builtin_bit_cast(unsigned, f);
  u += 0x7FFFu + ((u >> 16) & 1u);
  return (unsigned short)(u >> 16);
}

__device__ __forceinline__ float bflo(unsigned u) {
  return __builtin_bit_cast(float, u << 16);
}
__device__ __forceinline__ float bfhi(unsigned u) {
  return __builtin_bit_cast(float, u & 0xFFFF0000u);
}

__device__ __forceinline__ u32x2 plswap(unsigned a, unsigned b) {
#if __has_builtin(__builtin_amdgcn_permlane32_swap)
  return __builtin_amdgcn_permlane32_swap(a, b, false, false);
#else
  unsigned sa = (unsigned)__shfl_xor((int)a, 32, 64);
  unsigned sb = (unsigned)__shfl_xor((int)b, 32, 64);
  bool hi = (threadIdx.x & 63) >= 32;
  u32x2 r;
  r.x = hi ? sb : a;
  r.y = hi ? b : sa;
  return r;
#endif
}

// Async global->LDS: per-lane 16B lands at lds_base + lane*16.
__device__ __forceinline__ void stage16(const ushort* g, ushort* l, int lane) {
#if __has_builtin(__builtin_amdgcn_global_load_lds)
  __builtin_amdgcn_global_load_lds(
      (__attribute__((address_space(1))) unsigned int*)(unsigned long long)(
          const void*)g,
      (__attribute__((address_space(3))) unsigned int*)(unsigned)(
          unsigned long long)(const void*)l,
      16, 0, 0);
#else
  *(uint4*)(l + lane * 8) = *(const uint4*)g;
#endif
}

// ---------------------------------------------------------------------------
// Prep: transpose+convert fp32 sources into bf16 k-contiguous layouts.
// ---------------------------------------------------------------------------
__global__ __launch_bounds__(256) void prep_kernel(
    const float* __restrict__ x, const float* __restrict__ wqkv,
    const float* __restrict__ wout, ushort* __restrict__ xbf,
    ushort* __restrict__ wT, ushort* __restrict__ woT) {
  const int t = threadIdx.x;
  const int sub = t & 15, grp = t >> 4;
  const int id = blockIdx.x;
  const float* src;
  ushort* dst;
  int src_ld, k0, n0;
  float sc = 1.f;
  if (id < 512) {
    int mt = id & 63, kt = (id >> 6) & 3, b = id >> 8;
    src = x + (size_t)b * 256 * 4096;
    src_ld = 4096;
    dst = xbf + (size_t)b * 4096 * 256;
    k0 = kt * 64;
    n0 = mt * 64;
  } else if (id < 560) {
    int r = id - 512, nt = r % 12, kt = r / 12;
    src = wqkv;
    src_ld = 768;
    dst = wT;
    k0 = kt * 64;
    n0 = nt * 64;
    if (n0 < 256) sc = SL2E;
  } else {
    int r = id - 560, nt = r & 3, kt = r >> 2;
    src = wout;
    src_ld = 256;
    dst = woT;
    k0 = kt * 64;
    n0 = nt * 64;
  }
  const int k = k0 + grp * 4;
  const int n = n0 + sub * 4;
  unsigned d0[4], d1[4];
#pragma unroll
  for (int i = 0; i < 4; ++i) {
    float4 v = *(const float4*)(src + (size_t)(k + i) * src_ld + n);
    d0[i] = pkrne(v.x * sc, v.y * sc);
    d1[i] = pkrne(v.z * sc, v.w * sc);
  }
  u32x2 r0 = {__builtin_amdgcn_perm(d0[1], d0[0], 0x05040100u),
              __builtin_amdgcn_perm(d0[3], d0[2], 0x05040100u)};
  u32x2 r1 = {__builtin_amdgcn_perm(d0[1], d0[0], 0x07060302u),
              __builtin_amdgcn_perm(d0[3], d0[2], 0x07060302u)};
  u32x2 r2 = {__builtin_amdgcn_perm(d1[1], d1[0], 0x05040100u),
              __builtin_amdgcn_perm(d1[3], d1[2], 0x05040100u)};
  u32x2 r3 = {__builtin_amdgcn_perm(d1[1], d1[0], 0x07060302u),
              __builtin_amdgcn_perm(d1[3], d1[2], 0x07060302u)};
  *(u32x2*)(dst + (size_t)(n + 0) * 256 + k) = r0;
  *(u32x2*)(dst + (size_t)(n + 1) * 256 + k) = r1;
  *(u32x2*)(dst + (size_t)(n + 2) * 256 + k) = r2;
  *(u32x2*)(dst + (size_t)(n + 3) * 256 + k) = r3;
}

// ---------------------------------------------------------------------------
// Fused QKV: D[n][tok] = wT(rows n) x xbf(rows tok).
// Q stored [b,h][tok][dd]. K and V stored FRAGMENT-LINEAR per 64-token tile
// (1KB chunks in the exact order attn's lanes consume them):
//   K: (b*8+h)*131072 + tl*2048 + s*1024 + hK*512 + hi*256 + l5*8 + e
//   V: (b*8+h)*131072 + tl*2048 + s*1024 + hV*512 + hi*256 + d*8 + e
// ---------------------------------------------------------------------------
__global__ __launch_bounds__(256) void qkv_kernel(
    const ushort* __restrict__ xbf, const ushort* __restrict__ wT,
    const float* __restrict__ bq, ushort* __restrict__ QG,
    ushort* __restrict__ KG, ushort* __restrict__ VtG) {
  __shared__ __align__(16) ushort Wl[64][40];
  __shared__ __align__(16) ushort Xl[128][40];
  const int t0 = blockIdx.x * 128;
  const int n0 = blockIdx.y * 64;
  const int t = threadIdx.x;
  const int wid = t >> 6, lane = t & 63;
  const int wy = wid >> 1, wx = wid & 1;
  const int quad = lane >> 4, l16 = lane & 15;
  f32x4 acc[2][4] = {};
  const int wr = t >> 2, wsg = t & 3;
  for (int k0 = 0; k0 < 256; k0 += 32) {
    __syncthreads();
    *(uint4*)&Wl[wr][wsg * 8] =
        *(const uint4*)(wT + (size_t)(n0 + wr) * 256 + k0 + wsg * 8);
#pragma unroll
    for (int i = 0; i < 2; ++i) {
      int fid = t + 256 * i, row = fid >> 2, seg = fid & 3;
      *(uint4*)&Xl[row][seg * 8] =
          *(const uint4*)(xbf + (size_t)(t0 + row) * 256 + k0 + seg * 8);
    }
    __syncthreads();
    s16x8 wf[2], xf[4];
#pragma unroll
    for (int i = 0; i < 2; ++i)
      wf[i] = *(const s16x8*)&Wl[32 * wy + 16 * i + l16][quad * 8];
#pragma unroll
    for (int j = 0; j < 4; ++j)
      xf[j] = *(const s16x8*)&Xl[64 * wx + 16 * j + l16][quad * 8];
#pragma unroll
    for (int i = 0; i < 2; ++i)
#pragma unroll
      for (int j = 0; j < 4; ++j) acc[i][j] = MFMA32(wf[i], xf[j], acc[i][j]);
  }
  if (n0 < 256) {
    // Q: [b,h][tok][dd]
#pragma unroll
    for (int i = 0; i < 2; ++i) {
      int nb = n0 + 32 * wy + 16 * i + 4 * quad;
      float4 b4 = *(const float4*)(bq + nb);
      float bx0 = b4.x * SL2E, bx1 = b4.y * SL2E, bx2 = b4.z * SL2E,
            bx3 = b4.w * SL2E;
      int h = ((nb & 255) >> 5);
      int dd0 = nb & 31;
#pragma unroll
      for (int j = 0; j < 4; ++j) {
        int tok = t0 + 64 * wx + 16 * j + l16;
        int b = tok >> 12, tokn = tok & 4095;
        u32x2 pk = {pkrne(acc[i][j][0] + bx0, acc[i][j][1] + bx1),
                    pkrne(acc[i][j][2] + bx2, acc[i][j][3] + bx3)};
        *(u32x2*)(QG + ((size_t)(b * 8 + h) * 4096 + tokn) * 32 + dd0) = pk;
      }
    }
  } else if (n0 < 512) {
    // K: fragment-linear. dd0 = 16*i + 4*quad -> hK=i, hi=quad>>1,
    // e0=4*(quad&1).
#pragma unroll
    for (int i = 0; i < 2; ++i) {
      int nb = n0 + 32 * wy + 16 * i + 4 * quad;
      float4 b4 = *(const float4*)(bq + nb);
      float bx0 = b4.x, bx1 = b4.y, bx2 = b4.z, bx3 = b4.w;
      int h = ((nb & 255) >> 5);
      size_t fo = (size_t)i * 512 + (quad >> 1) * 256 + (quad & 1) * 4;
#pragma unroll
      for (int j = 0; j < 4; ++j) {
        int tok = t0 + 64 * wx + 16 * j + l16;
        int b = tok >> 12, tokn = tok & 4095;
        int tl = tokn >> 6, ss = (tokn >> 5) & 1, l5 = tokn & 31;
        u32x2 pk = {pkrne(acc[i][j][0] + bx0, acc[i][j][1] + bx1),
                    pkrne(acc[i][j][2] + bx2, acc[i][j][3] + bx3)};
        *(u32x2*)(KG + (size_t)(b * 8 + h) * 131072 + (size_t)tl * 2048 +
                  ss * 1024 + l5 * 8 + fo) = pk;
      }
    }
  } else {
    // V: fragment-linear.
#pragma unroll
    for (int i = 0; i < 2; ++i) {
      int nb = n0 + 32 * wy + 16 * i + 4 * quad;
      float4 b4 = *(const float4*)(bq + nb);
      float bb[4] = {b4.x, b4.y, b4.z, b4.w};
#pragma unroll
      for (int r = 0; r < 4; ++r) {
        int nn = nb + r - 512;
        int h = nn >> 5, d = nn & 31;
#pragma unroll
        for (int j = 0; j < 4; ++j) {
          int tok = t0 + 64 * wx + 16 * j + l16;
          int b = tok >> 12, tokn = tok & 4095;
          int tl = tokn >> 6, ss = (tokn >> 5) & 1;
          int hV = (tokn >> 4) & 1, hii = (tokn >> 3) & 1, e = tokn & 7;
          VtG[(size_t)(b * 8 + h) * 131072 + (size_t)tl * 2048 + ss * 1024 +
              hV * 512 + hii * 256 + d * 8 + e] = bfr(acc[i][j][r] + bb[r]);
        }
      }
    }
  }
}

// ---------------------------------------------------------------------------
// Flash attention, SPLIT-K x2, 32x32 MFMA, skewed pipeline with
// NON-DRAINING barriers (T3+T4): raw s_barrier + counted inline-asm
// vmcnt(2) -- prefetch loads stay in flight across the barrier (the r2/r4
// __syncthreads drained vmcnt(0) every iter, serializing the pipeline).
// 4 LDS buffers (32 KiB) + unroll-by-4 => all buffer offsets are
// compile-time constants, S1p ping-pongs via SSA (no copies), and one
// barrier/iter is WAR/RAW-safe at the <=1-iter drift raw barriers allow.
// QK MFMAs take a loop-invariant zero C operand (no per-iter 16-reg
// zero-init). setprio(1) brackets the QK MFMA clusters (T5).
// ---------------------------------------------------------------------------
__device__ __forceinline__ void softpv(const f32x16& S, const ushort* vhalf,
                                       int lane, f32x16& o, f32x16& o_l) {
  const s16x8 ones8 = {(short)0x3F80, (short)0x3F80, (short)0x3F80,
                       (short)0x3F80, (short)0x3F80, (short)0x3F80,
                       (short)0x3F80, (short)0x3F80};
  unsigned w8[8];
#pragma unroll
  for (int ii = 0; ii < 8; ++ii)
    w8[ii] = pktrunc(EXP2F(S[2 * ii]), EXP2F(S[2 * ii + 1]));
  u32x2 sw0 = plswap(w8[0], w8[2]);
  u32x2 sw1 = plswap(w8[1], w8[3]);
  u32x2 sw2 = plswap(w8[4], w8[6]);
  u32x2 sw3 = plswap(w8[5], w8[7]);
  u32x4 pa0 = {sw0.x, sw1.x, sw0.y, sw1.y};  // k 0..15 of subtile
  u32x4 pa1 = {sw2.x, sw3.x, sw2.y, sw3.y};  // k 16..31
  const s16x8 pA0 = __builtin_bit_cast(s16x8, pa0);
  const s16x8 pA1 = __builtin_bit_cast(s16x8, pa1);
  const s16x8 va0 = *(const s16x8*)(vhalf + lane * 8);
  const s16x8 va1 = *(const s16x8*)(vhalf + 512 + lane * 8);
  o = MFMA3216(pA0, va0, o);
  o = MFMA3216(pA1, va1, o);
  o_l = MFMA3216(pA0, ones8, o_l);
  o_l = MFMA3216(pA1, ones8, o_l);
}

// One k-tile step. CUR/PRV are compile-time buffer indices; SKEW: process
// prev tile's subtile-1; LAST: final tile (no stage, full vmcnt drain).
#define ATTN_STEP(CUR, PRV, SKEW, LAST)                                      \
  {                                                                          \
    if (!(LAST)) {                                                           \
      stage16(kpre, &KVs[((CUR) + 1) & 3][kdst], lane);                      \
      stage16(vpre, &KVs[((CUR) + 1) & 3][2048 + kdst], lane);               \
      kpre += 2048;                                                          \
      vpre += 2048;                                                          \
      asm volatile("s_waitcnt vmcnt(2)" ::: "memory");                       \
    } else {                                                                 \
      asm volatile("s_waitcnt vmcnt(0)" ::: "memory");                       \
    }                                                                        \
    __builtin_amdgcn_sched_barrier(0);                                       \
    __builtin_amdgcn_s_barrier();                                            \
    __builtin_amdgcn_sched_barrier(0);                                       \
    const ushort* kb = &KVs[(CUR)][0];                                       \
    const s16x8 ka00 = *(const s16x8*)(kb + lo8);                            \
    const s16x8 ka01 = *(const s16x8*)(kb + 512 + lo8);                      \
    __builtin_amdgcn_s_setprio(1);                                           \
    f32x16 S0 = MFMA3216(ka00, qf0, fz);                                     \
    S0 = MFMA3216(ka01, qf1, S0);                                            \
    __builtin_amdgcn_s_setprio(0);                                           \
    if (SKEW) softpv(S1p, &KVs[(PRV)][2048 + 1024], lane, o, o_l);           \
    const s16x8 ka10 = *(const s16x8*)(kb + 1024 + lo8);                     \
    const s16x8 ka11 = *(const s16x8*)(kb + 1536 + lo8);                     \
    __builtin_amdgcn_s_setprio(1);                                           \
    f32x16 S1 = MFMA3216(ka10, qf0, fz);                                     \
    S1 = MFMA3216(ka11, qf1, S1);                                            \
    __builtin_amdgcn_s_setprio(0);                                           \
    softpv(S0, &KVs[(CUR)][2048], lane, o, o_l);                             \
    S1p = S1;                                                                \
  }

__global__ __launch_bounds__(256, 4) void attn_split(
    const ushort* __restrict__ QG, const ushort* __restrict__ KG,
    const ushort* __restrict__ VtG, ushort* __restrict__ OF0,
    ushort* __restrict__ OFb, float* __restrict__ LF) {
  __shared__ __align__(64) ushort KVs[4][4096];  // per buf: K 2048, V 2048
  const int id = blockIdx.x;
  const int bh = (id & 7) * 2 + ((id >> 3) & 1);  // XCD-affine heads
  const int q0 = ((id >> 4) & 31) * 128;
  const int sp = id >> 9;   // split index 0..1
  const int kt0 = sp * 32;  // 32 k-tiles (64 tok each) per split
  const int t = threadIdx.x;
  const int wid = t >> 6, lane = t & 63;
  const int l5 = lane & 31, hi = lane >> 5;
  const ushort* qp = QG + (size_t)bh * 4096 * 32;
  const ushort* kgp = KG + (size_t)bh * 131072 + (size_t)kt0 * 2048;
  const ushort* vgp = VtG + (size_t)bh * 131072 + (size_t)kt0 * 2048;
  const int qw = q0 + 32 * wid;
  // Q fragments (held in regs): B[dk = h*16 + hi*8 + e][q = l5]
  const ushort* qrow = qp + (size_t)(qw + l5) * 32 + hi * 8;
  const s16x8 qf0 = *(const s16x8*)(qrow);
  const s16x8 qf1 = *(const s16x8*)(qrow + 16);
  // Staging: wave wid stages the 1KB chunk at kdst of both K and V.
  const int kdst = wid * 512;
  const ushort* kpre = kgp + kdst + lane * 8;
  const ushort* vpre = vgp + kdst + lane * 8;
  stage16(kpre, &KVs[0][kdst], lane);
  stage16(vpre, &KVs[0][2048 + kdst], lane);
  kpre += 2048;
  vpre += 2048;
  f32x16 o = {};
  f32x16 o_l = {};
  f32x16 S1p = {};
  const f32x16 fz = {};  // loop-invariant zero C operand for QK MFMAs
  const int lo8 = lane * 8;
  // iters 0..3 peeled (iter 0 has no skew), then 6 groups of 4, then
  // group 7 peeled (iter 31 is LAST).
  ATTN_STEP(0, 3, false, false)
  ATTN_STEP(1, 0, true, false)
  ATTN_STEP(2, 1, true, false)
  ATTN_STEP(3, 2, true, false)
  for (int g = 1; g < 7; ++g) {
    ATTN_STEP(0, 3, true, false)
    ATTN_STEP(1, 0, true, false)
    ATTN_STEP(2, 1, true, false)
    ATTN_STEP(3, 2, true, false)
  }
  ATTN_STEP(0, 3, true, false)
  ATTN_STEP(1, 0, true, false)
  ATTN_STEP(2, 1, true, false)
  ATTN_STEP(3, 2, true, true)
  // Epilogue: subtile 1 of the last tile (buffer 3).
  softpv(S1p, &KVs[3][2048 + 1024], lane, o, o_l);
  // Store un-normalized bf16 partial O + f32 partial l.
  ushort* OFs = (sp == 0) ? OF0 : OFb;
  float* LFs = LF + (size_t)sp * 65536;
#pragma unroll
  for (int r = 0; r < 16; ++r) {
    int q = qw + (r & 3) + 8 * (r >> 2) + 4 * hi;
    OFs[((size_t)bh * 4096 + q) * 32 + l5] = bfr(o[r]);
  }
  // o_l: C[row=q][col=d], l[q] replicated across d. Lanes l5<16 store row
  // r=l5 of their hi-half.
  float lval = o_l[0];
#pragma unroll
  for (int r = 1; r < 16; ++r) lval = (l5 == r) ? o_l[r] : lval;
  if (l5 < 16)
    LFs[(size_t)bh * 4096 + qw + (l5 & 3) + 8 * (l5 >> 2) + 4 * hi] = lval;
}

// ---------------------------------------------------------------------------
// Out-proj with fused 2-way split-combine + normalization in the staging.
// 64-token tiles -> grid (128,4) = 2 blocks/CU.
// ---------------------------------------------------------------------------
__global__ __launch_bounds__(256) void proj_split(
    const ushort* __restrict__ OF0, const ushort* __restrict__ OFb,
    const float* __restrict__ LF, const ushort* __restrict__ woT,
    const float* __restrict__ bo, float* __restrict__ out) {
  __shared__ __align__(16) ushort Wl[64][40];
  __shared__ __align__(16) ushort Xl[64][40];
  const int t0 = blockIdx.x * 64;
  const int c0 = blockIdx.y * 64;
  const int t = threadIdx.x;
  const int wid = t >> 6, lane = t & 63;
  const int wy = wid >> 1, wx = wid & 1;
  const int quad = lane >> 4, l16 = lane & 15;
  f32x4 acc[2][2] = {};
  const int wr = t >> 2, wsg = t & 3;
  const int c8 = (t & 7) * 4;  // dd column (4 ushorts)
  for (int k0 = 0; k0 < 256; k0 += 32) {
    __syncthreads();
    *(uint4*)&Wl[wr][wsg * 8] =
        *(const uint4*)(woT + (size_t)(c0 + wr) * 256 + k0 + wsg * 8);
    const int hh = k0 >> 5;
#pragma unroll
    for (int p = 0; p < 2; ++p) {
      int row = 32 * p + (t >> 3);
      int tok = t0 + row, bb = tok >> 12, tokn = tok & 4095;
      size_t ro = (size_t)(bb * 8 + hh) * 4096 + tokn;
      size_t oi = ro * 32 + c8;
      uint2 a0 = *(const uint2*)(OF0 + oi);
      uint2 a1 = *(const uint2*)(OFb + oi);
      float l = LF[ro] + LF[65536 + ro];
      float inv = RCPF(l);
      f32x4 s;
      s[0] = bflo(a0.x) + bflo(a1.x);
      s[1] = bfhi(a0.x) + bfhi(a1.x);
      s[2] = bflo(a0.y) + bflo(a1.y);
      s[3] = bfhi(a0.y) + bfhi(a1.y);
      s *= inv;
      u32x2 pk = {pkrne(s[0], s[1]), pkrne(s[2], s[3])};
      *(u32x2*)&Xl[row][c8] = pk;
    }
    __syncthreads();
    s16x8 wf[2], xf[2];
#pragma unroll
    for (int i = 0; i < 2; ++i)
      wf[i] = *(const s16x8*)&Wl[32 * wy + 16 * i + l16][quad * 8];
#pragma unroll
    for (int j = 0; j < 2; ++j)
      xf[j] = *(const s16x8*)&Xl[32 * wx + 16 * j + l16][quad * 8];
#pragma unroll
    for (int i = 0; i < 2; ++i)
#pragma unroll
      for (int j = 0; j < 2; ++j) acc[i][j] = MFMA32(wf[i], xf[j], acc[i][j]);
  }
#pragma unroll
  for (int i = 0; i < 2; ++i) {
    int cb = c0 + 32 * wy + 16 * i + 4 * quad;
    float4 b4 = *(const float4*)(bo + cb);
    float bb[4] = {b4.x, b4.y, b4.z, b4.w};
#pragma unroll
    for (int j = 0; j < 2; ++j) {
      int tok = t0 + 32 * wx + 16 * j + l16;
      int b = tok >> 12, tokn = tok & 4095;
#pragma unroll
      for (int r = 0; r < 4; ++r)
        out[((size_t)(b * 256 + cb + r)) * 4096 + tokn] = acc[i][j][r] + bb[r];
    }
  }
}

extern "C" void kernel_launch(void* const* d_in, const int* in_sizes, int n_in,
                              void* d_out, int out_size, void* d_ws, size_t ws_size,
                              hipStream_t stream) {
  (void)in_sizes; (void)n_in; (void)out_size; (void)ws_size;
  const float* x = (const float*)d_in[0];
  const float* wq = (const float*)d_in[1];
  const float* bq = (const float*)d_in[2];
  const float* wo = (const float*)d_in[3];
  const float* bo = (const float*)d_in[4];
  float* out = (float*)d_out;
  ushort* ws = (ushort*)d_ws;
  // ws layout:
  ushort* xbf = ws;                    // [8192][256]  (dead after qkv)
  ushort* OF0 = ws;                    // split0 partial O overlays dead xbf
  ushort* QG  = ws + 2097152;          // [2][8][4096][32]
  ushort* KG  = ws + 4194304;          // fragment-linear tiles
  ushort* VtG = ws + 6291456;          // fragment-linear tiles
  ushort* wT  = ws + 8388608;          // [768][256]
  ushort* woT = ws + 8585216;          // [256][256]
  ushort* OFb = ws + 8650752;          // split1 partial O: 2,097,152 ushorts
  float* LF = (float*)(ws + 12845056); // [2][16][4096] f32
  prep_kernel<<<576, 256, 0, stream>>>(x, wq, wo, xbf, wT, woT);
  qkv_kernel<<<dim3(64, 12), 256, 0, stream>>>(xbf, wT, bq, QG, KG, VtG);
  attn_split<<<1024, 256, 0, stream>>>(QG, KG, VtG, OF0, OFb, LF);
  proj_split<<<dim3(128, 4), 256, 0, stream>>>(OF0, OFb, LF, woT, bo, out);
}